// Round 1
// baseline (1316.383 us; speedup 1.0000x reference)
//
#include <hip/hip_runtime.h>

// ---------------- types ----------------
typedef __attribute__((ext_vector_type(8))) short short8;
typedef __attribute__((ext_vector_type(8))) unsigned short us8;
typedef __attribute__((ext_vector_type(4))) float f32x4;

#define C_DIM 1024
#define L_DIM 4096
#define B_DIM 8
#define H_DIM 8
#define HD 128
#define CHUNK 64
#define K2 2048   // split K (hi | lo)

// round-to-nearest-even fp32 -> bf16 (raw bits)
__device__ inline unsigned short bf16_hi(float f) {
    unsigned u = __float_as_uint(f);
    unsigned r = (u + 0x7FFFu + ((u >> 16) & 1u)) >> 16;
    return (unsigned short)r;
}
__device__ inline float bf16_to_f(unsigned short h) {
    return __uint_as_float(((unsigned)h) << 16);
}
__device__ inline void split2(float f, unsigned short& hi, unsigned short& lo) {
    hi = bf16_hi(f);
    lo = bf16_hi(f - bf16_to_f(hi));
}

// ---------------- weight split+transpose: W[K][N] fp32 -> Wt[N][2K] bf16 ----------------
__global__ void split_w(const float* __restrict__ W, unsigned short* __restrict__ Wt) {
    __shared__ float tile[32][33];
    int nb = blockIdx.x * 32;  // n base
    int kb = blockIdx.y * 32;  // k base
    for (int i = 0; i < 4; ++i)
        tile[threadIdx.y + i * 8][threadIdx.x] =
            W[(size_t)(kb + threadIdx.y + i * 8) * C_DIM + nb + threadIdx.x];
    __syncthreads();
    for (int i = 0; i < 4; ++i) {
        int n = nb + threadIdx.y + i * 8;
        int k = kb + threadIdx.x;
        float v = tile[threadIdx.x][threadIdx.y + i * 8]; // = W[k][n]
        unsigned short hi, lo; split2(v, hi, lo);
        Wt[(size_t)n * K2 + k] = hi;
        Wt[(size_t)n * K2 + C_DIM + k] = lo;
    }
}

// ------------- x transpose+split: x[b][c][l] -> xsp[(b-b0)*L + l][2C] bf16 -------------
__global__ void split_x(const float* __restrict__ x, unsigned short* __restrict__ xsp, int b0) {
    __shared__ float tile[32][33];
    int lb = blockIdx.x * 32, cb = blockIdx.y * 32, bp = blockIdx.z;
    const float* xp = x + ((size_t)(b0 + bp) * C_DIM + cb) * L_DIM + lb;
    for (int i = 0; i < 4; ++i)
        tile[threadIdx.y + i * 8][threadIdx.x] = xp[(size_t)(threadIdx.y + i * 8) * L_DIM + threadIdx.x];
    __syncthreads();
    for (int i = 0; i < 4; ++i) {
        size_t row = (size_t)bp * L_DIM + lb + threadIdx.y + i * 8;
        int c = cb + threadIdx.x;
        float v = tile[threadIdx.x][threadIdx.y + i * 8]; // = x[b][c][l]
        unsigned short hi, lo; split2(v, hi, lo);
        xsp[row * K2 + c] = hi;
        xsp[row * K2 + C_DIM + c] = lo;
    }
}

// ---------------- bf16 MFMA GEMM: Y[M][N] = A[M][K] * Bt[N][K]^T + bias ----------------
#define TM 128
#define TN 128
#define BK 64
#define LDSS 72   // LDS row stride (bf16 elems): +8 pad -> 2-way-only bank aliasing

__global__ __launch_bounds__(256) void gemm_bf16(
    const unsigned short* __restrict__ A,   // [M][K] k-contig bf16 bits
    const unsigned short* __restrict__ Bt,  // [N][K] k-contig bf16 bits
    const float* __restrict__ bias,         // [N]
    float* __restrict__ Y,                  // [M][N] fp32
    int M, int N, int K)
{
    __shared__ unsigned short As[TM * LDSS];
    __shared__ unsigned short Bs[TN * LDSS];
    int t = threadIdx.x;
    int m0 = blockIdx.y * TM, n0 = blockIdx.x * TN;
    int wave = t >> 6, lane = t & 63;
    int wr = wave >> 1, wc = wave & 1;
    int lm = lane & 15, quad = lane >> 4;

    f32x4 acc[4][4];
    for (int i = 0; i < 4; ++i)
        for (int j = 0; j < 4; ++j) { f32x4 z = {0.f, 0.f, 0.f, 0.f}; acc[i][j] = z; }

    const int lrow = t >> 3;        // 0..31
    const int lk = (t & 7) * 8;     // 0..56

    for (int kt = 0; kt < K; kt += BK) {
#pragma unroll
        for (int p = 0; p < 4; ++p) {
            int r = p * 32 + lrow;
            *(us8*)&As[r * LDSS + lk] = *(const us8*)&A[(size_t)(m0 + r) * K + kt + lk];
            *(us8*)&Bs[r * LDSS + lk] = *(const us8*)&Bt[(size_t)(n0 + r) * K + kt + lk];
        }
        __syncthreads();
#pragma unroll
        for (int s = 0; s < 2; ++s) {
            short8 af[4], bfr[4];
#pragma unroll
            for (int i = 0; i < 4; ++i)
                af[i] = *(const short8*)&As[(wr * 64 + i * 16 + lm) * LDSS + s * 32 + quad * 8];
#pragma unroll
            for (int j = 0; j < 4; ++j)
                bfr[j] = *(const short8*)&Bs[(wc * 64 + j * 16 + lm) * LDSS + s * 32 + quad * 8];
#pragma unroll
            for (int i = 0; i < 4; ++i)
#pragma unroll
                for (int j = 0; j < 4; ++j)
                    acc[i][j] = __builtin_amdgcn_mfma_f32_16x16x32_bf16(af[i], bfr[j], acc[i][j], 0, 0, 0);
        }
        __syncthreads();
    }

    // epilogue: C/D mapping col=lane&15, row=quad*4+reg  [verified m89/m91]
#pragma unroll
    for (int i = 0; i < 4; ++i) {
        int row = m0 + wr * 64 + i * 16 + quad * 4;
#pragma unroll
        for (int j = 0; j < 4; ++j) {
            int col = n0 + wc * 64 + j * 16 + lm;
            float b = bias[col];
#pragma unroll
            for (int r = 0; r < 4; ++r)
                Y[(size_t)(row + r) * N + col] = acc[i][j][r] + b;
        }
    }
}

// ---------------- attention: one block per (b', chunk, head), fp32 ----------------
__global__ __launch_bounds__(256) void attn(
    const float* __restrict__ Qt, const float* __restrict__ Kt, const float* __restrict__ Vt,
    unsigned short* __restrict__ Osp)  // [BG*L][2C] bf16 split
{
    // bufQK: phase1 = Qhalf(64x65) + Khalf(64x64); phase3 = V(64x128); epi = O(64x129)
    __shared__ float bufQK[64 * 65 + 64 * 64];  // 8256 floats
    __shared__ float Ss[64 * 65];

    int t = threadIdx.x;
    int idx = blockIdx.x;
    int h = idx & 7;
    int chunk = (idx >> 3) & 63;
    int bp = idx >> 9;
    size_t rowbase = (size_t)bp * L_DIM + (size_t)chunk * CHUNK;
    const float* Qp = Qt + rowbase * C_DIM + h * HD;
    const float* Kp = Kt + rowbase * C_DIM + h * HD;
    const float* Vp = Vt + rowbase * C_DIM + h * HD;
    int wave = t >> 6, lane = t & 63;

    float sacc[16];
#pragma unroll
    for (int i = 0; i < 16; ++i) sacc[i] = 0.f;

    float* Qh = bufQK;            // stride 65 (lane-indexed reads: 2-way, free)
    float* Kh = bufQK + 64 * 65;  // stride 64 (wave-uniform reads: broadcast)

    for (int dh = 0; dh < HD; dh += 64) {
#pragma unroll
        for (int p = 0; p < 4; ++p) {
            int f = p * 256 + t;
            int row = f >> 4, col = (f & 15) * 4;
            float4 q4 = *(const float4*)&Qp[(size_t)row * C_DIM + dh + col];
            float4 k4 = *(const float4*)&Kp[(size_t)row * C_DIM + dh + col];
            Qh[row * 65 + col + 0] = q4.x; Qh[row * 65 + col + 1] = q4.y;
            Qh[row * 65 + col + 2] = q4.z; Qh[row * 65 + col + 3] = q4.w;
            *(float4*)&Kh[row * 64 + col] = k4;
        }
        __syncthreads();
        // lane = q row; this wave covers k in [wave*16, wave*16+16)
        for (int d = 0; d < 64; ++d) {
            float qv = Qh[lane * 65 + d];
            const float* kp = &Kh[(wave * 16) * 64 + d];
#pragma unroll
            for (int kk = 0; kk < 16; ++kk)
                sacc[kk] += qv * kp[kk * 64];
        }
        __syncthreads();
    }

    const float scale = 0.08838834764831845f;  // 1/sqrt(128)
#pragma unroll
    for (int kk = 0; kk < 16; ++kk)
        Ss[lane * 65 + wave * 16 + kk] = sacc[kk] * scale;
    __syncthreads();

    // softmax rows (threads 0..63), V load concurrent (bufQK is free now)
    float* Vs = bufQK;  // stride 128
#pragma unroll
    for (int p = 0; p < 8; ++p) {
        int f = p * 256 + t;
        int row = f >> 5, col = (f & 31) * 4;
        *(float4*)&Vs[row * 128 + col] = *(const float4*)&Vp[(size_t)row * C_DIM + col];
    }
    if (t < 64) {
        float mx = -1e30f;
        for (int k = 0; k < 64; ++k) mx = fmaxf(mx, Ss[t * 65 + k]);
        float sum = 0.f;
        for (int k = 0; k < 64; ++k) { float e = __expf(Ss[t * 65 + k] - mx); Ss[t * 65 + k] = e; sum += e; }
        float inv = 1.0f / sum;
        for (int k = 0; k < 64; ++k) Ss[t * 65 + k] *= inv;
    }
    __syncthreads();

    // O = P @ V ; lane = q row, wave covers d in [wave*32, wave*32+32)
    float oacc[32];
#pragma unroll
    for (int i = 0; i < 32; ++i) oacc[i] = 0.f;
    for (int k = 0; k < 64; ++k) {
        float p = Ss[lane * 65 + k];
        const float* vrow = &Vs[k * 128 + wave * 32];
#pragma unroll
        for (int dd = 0; dd < 32; ++dd)
            oacc[dd] += p * vrow[dd];
    }
    __syncthreads();  // before overwriting Vs with O staging
    float* Os = bufQK;  // stride 129 (conflict-free lane-row writes)
#pragma unroll
    for (int dd = 0; dd < 32; ++dd)
        Os[lane * 129 + wave * 32 + dd] = oacc[dd];
    __syncthreads();

    // write split-bf16 O: thread -> (row = t>>2, 32 contiguous d)
    {
        int row = t >> 2, dstart = (t & 3) * 32;
        size_t orow = (rowbase + row) * K2 + h * HD + dstart;
#pragma unroll
        for (int c = 0; c < 4; ++c) {
            us8 hv, lv;
#pragma unroll
            for (int i = 0; i < 8; ++i) {
                float v = Os[row * 129 + dstart + c * 8 + i];
                unsigned short hi, lo; split2(v, hi, lo);
                hv[i] = (short)hi; lv[i] = (short)lo;
            }
            *(us8*)&Osp[orow + c * 8] = hv;
            *(us8*)&Osp[orow + C_DIM + c * 8] = lv;
        }
    }
}

// ---------------- final transpose: Y[(b'*L + l)][c] -> out[b][c][l] ----------------
__global__ void trans_out(const float* __restrict__ Y, float* __restrict__ out, int b0) {
    __shared__ float tile[32][33];
    int lb = blockIdx.x * 32, cb = blockIdx.y * 32, bp = blockIdx.z;
    const float* Yp = Y + ((size_t)bp * L_DIM + lb) * C_DIM + cb;
    for (int i = 0; i < 4; ++i)
        tile[threadIdx.y + i * 8][threadIdx.x] = Yp[(size_t)(threadIdx.y + i * 8) * C_DIM + threadIdx.x];
    __syncthreads();
    float* op = out + ((size_t)(b0 + bp) * C_DIM + cb) * L_DIM + lb;
    for (int i = 0; i < 4; ++i)
        op[(size_t)(threadIdx.y + i * 8) * L_DIM + threadIdx.x] = tile[threadIdx.x][threadIdx.y + i * 8];
}

// ---------------- host ----------------
extern "C" void kernel_launch(void* const* d_in, const int* in_sizes, int n_in,
                              void* d_out, int out_size, void* d_ws, size_t ws_size,
                              hipStream_t stream) {
    const float* x  = (const float*)d_in[0];
    const float* Wq = (const float*)d_in[1];
    const float* bq = (const float*)d_in[2];
    const float* Wk = (const float*)d_in[3];
    const float* bk = (const float*)d_in[4];
    const float* Wv = (const float*)d_in[5];
    const float* bv = (const float*)d_in[6];
    const float* Wo = (const float*)d_in[7];
    const float* bo = (const float*)d_in[8];
    float* out = (float*)d_out;

    const size_t MB = 1024ull * 1024ull;
    char* base = (char*)d_ws;
    unsigned short* WspQ = (unsigned short*)(base + 0 * 4 * MB);
    unsigned short* WspK = (unsigned short*)(base + 1 * 4 * MB);
    unsigned short* WspV = (unsigned short*)(base + 2 * 4 * MB);
    unsigned short* WspO = (unsigned short*)(base + 3 * 4 * MB);

    // batch group size: ws need = 16MiB (weights) + BG*64MiB
    int BG = 8;
    while (BG > 1 && 16 * MB + (size_t)BG * 64 * MB > ws_size) BG >>= 1;

    char* p = base + 16 * MB;
    unsigned short* xsp = (unsigned short*)p;                 // [BG*L][2C] bf16; aliased as Osp
    float* Qt = (float*)(p + (size_t)BG * 16 * MB);           // [BG*L][C] fp32; aliased as Y
    float* Kt = (float*)(p + (size_t)BG * 32 * MB);
    float* Vt = (float*)(p + (size_t)BG * 48 * MB);

    dim3 tb(32, 8);
    split_w<<<dim3(32, 32), tb, 0, stream>>>(Wq, WspQ);
    split_w<<<dim3(32, 32), tb, 0, stream>>>(Wk, WspK);
    split_w<<<dim3(32, 32), tb, 0, stream>>>(Wv, WspV);
    split_w<<<dim3(32, 32), tb, 0, stream>>>(Wo, WspO);

    for (int b0 = 0; b0 < B_DIM; b0 += BG) {
        int M = BG * L_DIM;
        split_x<<<dim3(L_DIM / 32, C_DIM / 32, BG), tb, 0, stream>>>(x, xsp, b0);
        dim3 gg(C_DIM / TN, M / TM);
        gemm_bf16<<<gg, 256, 0, stream>>>(xsp, WspQ, bq, Qt, M, C_DIM, K2);
        gemm_bf16<<<gg, 256, 0, stream>>>(xsp, WspK, bk, Kt, M, C_DIM, K2);
        gemm_bf16<<<gg, 256, 0, stream>>>(xsp, WspV, bv, Vt, M, C_DIM, K2);
        attn<<<BG * (L_DIM / CHUNK) * H_DIM, 256, 0, stream>>>(Qt, Kt, Vt, xsp);
        gemm_bf16<<<gg, 256, 0, stream>>>(xsp, WspO, bo, Qt, M, C_DIM, K2);
        trans_out<<<dim3(L_DIM / 32, C_DIM / 32, BG), tb, 0, stream>>>(Qt, out, b0);
    }
}